// Round 2
// baseline (15133.870 us; speedup 1.0000x reference)
//
#include <hip/hip_runtime.h>
#include <hip/hip_bf16.h>
#include <math.h>

// Problem constants
#define Bn   8
#define Sn   1024
#define Dn   512
#define Hn   8
#define DKn  64
#define Ln   6
#define DFFn 2048
#define Mn   (Bn * Sn)   // 8192 rows

// ---------------------------------------------------------------------------
// GEMM: C[M,N] = act(A[M,K] @ W[K,N] + bias[N])   (all fp32)
// 64x64 tile, 256 threads, 4x4 micro-tile, BK=16. fp32 accumulate.
// ---------------------------------------------------------------------------
template <int ACT>
__global__ __launch_bounds__(256) void k_gemm_bias(
    const float* __restrict__ A, const float* __restrict__ W,
    const float* __restrict__ bias, float* __restrict__ C,
    int M, int N, int K)
{
    __shared__ float As[16][68];   // [k][m], padded
    __shared__ float Bs[16][68];   // [k][n]
    const int tid = threadIdx.x;
    const int tx = tid & 15, ty = tid >> 4;
    const int bm = blockIdx.y * 64, bn = blockIdx.x * 64;

    float acc[4][4] = {{0.0f}};

    for (int k0 = 0; k0 < K; k0 += 16) {
        #pragma unroll
        for (int i = 0; i < 4; i++) {           // A tile 64x16
            int idx = tid + i * 256;
            int m = idx >> 4, k = idx & 15;
            As[k][m] = A[(size_t)(bm + m) * K + (k0 + k)];
        }
        #pragma unroll
        for (int i = 0; i < 4; i++) {           // B tile 16x64
            int idx = tid + i * 256;
            int k = idx >> 6, n = idx & 63;
            Bs[k][n] = W[(size_t)(k0 + k) * N + (bn + n)];
        }
        __syncthreads();
        #pragma unroll
        for (int k = 0; k < 16; k++) {
            float a[4], b[4];
            #pragma unroll
            for (int i = 0; i < 4; i++) a[i] = As[k][ty * 4 + i];
            #pragma unroll
            for (int j = 0; j < 4; j++) b[j] = Bs[k][tx * 4 + j];
            #pragma unroll
            for (int i = 0; i < 4; i++)
                #pragma unroll
                for (int j = 0; j < 4; j++)
                    acc[i][j] = fmaf(a[i], b[j], acc[i][j]);
        }
        __syncthreads();
    }

    #pragma unroll
    for (int i = 0; i < 4; i++) {
        int m = bm + ty * 4 + i;
        #pragma unroll
        for (int j = 0; j < 4; j++) {
            int n = bn + tx * 4 + j;
            float v = acc[i][j] + bias[n];
            if (ACT == 1) v = fmaxf(v, 0.0f);
            C[(size_t)m * N + n] = v;
        }
    }
}

// ---------------------------------------------------------------------------
// Causal attention. qkv: [M, 3D] fp32 rows = [q | k | v], head h at h*64.
// One block (256 thr) per (b, h, q). Scores for keys 0..q in LDS, softmax,
// then weighted V sum. Output o: [M, D] fp32.
// ---------------------------------------------------------------------------
__global__ __launch_bounds__(256) void k_attn(const float* __restrict__ qkv,
                                              float* __restrict__ o)
{
    const int q   = blockIdx.x;
    const int h   = blockIdx.y;
    const int b   = blockIdx.z;
    const int tid = threadIdx.x;
    const int nk  = q + 1;

    __shared__ float qv[DKn];
    __shared__ float sc[Sn];
    __shared__ float red[256];

    const size_t rowq = (size_t)(b * Sn + q) * (3 * Dn);
    if (tid < DKn) qv[tid] = qkv[rowq + h * DKn + tid];
    __syncthreads();

    // phase 1: scores
    float lmax = -1e30f;
    for (int j = tid; j < nk; j += 256) {
        const float* krow = qkv + (size_t)(b * Sn + j) * (3 * Dn) + Dn + h * DKn;
        float s = 0.0f;
        #pragma unroll
        for (int c = 0; c < DKn; c += 4) {
            float4 kk = *(const float4*)(krow + c);
            s += qv[c] * kk.x + qv[c + 1] * kk.y + qv[c + 2] * kk.z + qv[c + 3] * kk.w;
        }
        s *= 0.125f;   // 1/sqrt(64)
        sc[j] = s;
        lmax = fmaxf(lmax, s);
    }
    red[tid] = lmax;
    __syncthreads();
    for (int s2 = 128; s2 > 0; s2 >>= 1) {
        if (tid < s2) red[tid] = fmaxf(red[tid], red[tid + s2]);
        __syncthreads();
    }
    const float m = red[0];
    __syncthreads();

    // phase 2: exp + sum
    float lsum = 0.0f;
    for (int j = tid; j < nk; j += 256) {
        float p = __expf(sc[j] - m);
        sc[j] = p;
        lsum += p;
    }
    red[tid] = lsum;
    __syncthreads();
    for (int s2 = 128; s2 > 0; s2 >>= 1) {
        if (tid < s2) red[tid] += red[tid + s2];
        __syncthreads();
    }
    const float l = red[0];
    __syncthreads();

    // phase 3: O = P @ V  (thread = (dim d, key-chunk))
    const int d = tid & 63, chunk = tid >> 6;
    float part = 0.0f;
    for (int j = chunk; j < nk; j += 4) {
        const float* vrow = qkv + (size_t)(b * Sn + j) * (3 * Dn) + 2 * Dn + h * DKn;
        part += sc[j] * vrow[d];
    }
    red[tid] = part;
    __syncthreads();
    if (chunk == 0) {
        float sum = red[d] + red[64 + d] + red[128 + d] + red[192 + d];
        o[(size_t)(b * Sn + q) * Dn + h * DKn + d] = sum / l;
    }
}

// ---------------------------------------------------------------------------
// x = LayerNorm(t + x) * g + b   (row = 512 elems, biased var, eps 1e-5)
// ---------------------------------------------------------------------------
__device__ inline float block_reduce_sum(float v, float* red, int tid) {
    red[tid] = v;
    __syncthreads();
    for (int s = 128; s > 0; s >>= 1) {
        if (tid < s) red[tid] += red[tid + s];
        __syncthreads();
    }
    float r = red[0];
    __syncthreads();
    return r;
}

__global__ __launch_bounds__(256) void k_residual_ln(
    const float* __restrict__ t, float* __restrict__ x,
    const float* __restrict__ g, const float* __restrict__ be)
{
    __shared__ float red[256];
    const int row = blockIdx.x, tid = threadIdx.x;
    const size_t base = (size_t)row * Dn;

    float v0 = t[base + tid] + x[base + tid];
    float v1 = t[base + 256 + tid] + x[base + 256 + tid];

    float mean = block_reduce_sum(v0 + v1, red, tid) * (1.0f / Dn);
    float d0 = v0 - mean, d1 = v1 - mean;
    float var = block_reduce_sum(d0 * d0 + d1 * d1, red, tid) * (1.0f / Dn);
    float inv = rsqrtf(var + 1e-5f);

    x[base + tid]       = d0 * inv * g[tid]       + be[tid];
    x[base + 256 + tid] = d1 * inv * g[256 + tid] + be[256 + tid];
}

// ---------------------------------------------------------------------------
// launcher
// ---------------------------------------------------------------------------
extern "C" void kernel_launch(void* const* d_in, const int* in_sizes, int n_in,
                              void* d_out, int out_size, void* d_ws, size_t ws_size,
                              hipStream_t stream)
{
    const float* x_in   = (const float*)d_in[0];
    const float* qkv_w  = (const float*)d_in[1];
    const float* qkv_b  = (const float*)d_in[2];
    const float* out_w  = (const float*)d_in[3];
    const float* out_b  = (const float*)d_in[4];
    const float* ln1_g  = (const float*)d_in[5];
    const float* ln1_b  = (const float*)d_in[6];
    const float* mlp_w1 = (const float*)d_in[7];
    const float* mlp_b1 = (const float*)d_in[8];
    const float* mlp_w2 = (const float*)d_in[9];
    const float* mlp_b2 = (const float*)d_in[10];
    const float* ln2_g  = (const float*)d_in[11];
    const float* ln2_b  = (const float*)d_in[12];

    // workspace layout (fp32): X (16MB) | BUF1 (64MB, qkv & mlp-h) | BUF2 (16MB)
    // BUF3 (pre-LN temp, 16MB) lives in d_out — overwritten each layer, final
    // result copied into d_out at the end.
    float* X    = (float*)d_ws;
    float* BUF1 = X + (size_t)Mn * Dn;
    float* BUF2 = BUF1 + (size_t)Mn * DFFn;
    float* BUF3 = (float*)d_out;

    const size_t xBytes = (size_t)Mn * Dn * sizeof(float);
    hipMemcpyAsync(X, x_in, xBytes, hipMemcpyDeviceToDevice, stream);

    for (int l = 0; l < Ln; l++) {
        // QKV projection: [M,512] @ [512,1536]
        k_gemm_bias<0><<<dim3((3 * Dn) / 64, Mn / 64), 256, 0, stream>>>(
            X, qkv_w + (size_t)l * Dn * 3 * Dn, qkv_b + (size_t)l * 3 * Dn,
            BUF1, Mn, 3 * Dn, Dn);
        // causal attention
        k_attn<<<dim3(Sn, Hn, Bn), 256, 0, stream>>>(BUF1, BUF2);
        // output projection: [M,512] @ [512,512]
        k_gemm_bias<0><<<dim3(Dn / 64, Mn / 64), 256, 0, stream>>>(
            BUF2, out_w + (size_t)l * Dn * Dn, out_b + (size_t)l * Dn,
            BUF3, Mn, Dn, Dn);
        // x = LN(proj + x)
        k_residual_ln<<<Mn, 256, 0, stream>>>(BUF3, X, ln1_g + (size_t)l * Dn, ln1_b + (size_t)l * Dn);
        // MLP up + ReLU: [M,512] @ [512,2048]
        k_gemm_bias<1><<<dim3(DFFn / 64, Mn / 64), 256, 0, stream>>>(
            X, mlp_w1 + (size_t)l * Dn * DFFn, mlp_b1 + (size_t)l * DFFn,
            BUF1, Mn, DFFn, Dn);
        // MLP down: [M,2048] @ [2048,512]
        k_gemm_bias<0><<<dim3(Dn / 64, Mn / 64), 256, 0, stream>>>(
            BUF1, mlp_w2 + (size_t)l * DFFn * Dn, mlp_b2 + (size_t)l * Dn,
            BUF3, Mn, Dn, DFFn);
        // x = LN(x + mlp)
        k_residual_ln<<<Mn, 256, 0, stream>>>(BUF3, X, ln2_g + (size_t)l * Dn, ln2_b + (size_t)l * Dn);
    }

    hipMemcpyAsync(d_out, X, xBytes, hipMemcpyDeviceToDevice, stream);
}

// Round 3
// 7223.156 us; speedup vs baseline: 2.0952x; 2.0952x over previous
//
#include <hip/hip_runtime.h>
#include <hip/hip_bf16.h>
#include <math.h>

// Problem constants
#define Bn   8
#define Sn   1024
#define Dn   512
#define Hn   8
#define DKn  64
#define Ln   6
#define DFFn 2048
#define Mn   (Bn * Sn)   // 8192 rows

// ---------------------------------------------------------------------------
// GEMM: C[M,N] = act(A[M,K] @ W[K,N] + bias[N])   (all fp32)
// 64x64 tile, 256 threads, 4x4 micro-tile, BK=16. fp32 accumulate.
// ---------------------------------------------------------------------------
template <int ACT>
__global__ __launch_bounds__(256) void k_gemm_bias(
    const float* __restrict__ A, const float* __restrict__ W,
    const float* __restrict__ bias, float* __restrict__ C,
    int M, int N, int K)
{
    __shared__ float As[16][68];   // [k][m], padded
    __shared__ float Bs[16][68];   // [k][n]
    const int tid = threadIdx.x;
    const int tx = tid & 15, ty = tid >> 4;
    const int bm = blockIdx.y * 64, bn = blockIdx.x * 64;

    float acc[4][4] = {{0.0f}};

    for (int k0 = 0; k0 < K; k0 += 16) {
        #pragma unroll
        for (int i = 0; i < 4; i++) {           // A tile 64x16
            int idx = tid + i * 256;
            int m = idx >> 4, k = idx & 15;
            As[k][m] = A[(size_t)(bm + m) * K + (k0 + k)];
        }
        #pragma unroll
        for (int i = 0; i < 4; i++) {           // B tile 16x64
            int idx = tid + i * 256;
            int k = idx >> 6, n = idx & 63;
            Bs[k][n] = W[(size_t)(k0 + k) * N + (bn + n)];
        }
        __syncthreads();
        #pragma unroll
        for (int k = 0; k < 16; k++) {
            float a[4], b[4];
            #pragma unroll
            for (int i = 0; i < 4; i++) a[i] = As[k][ty * 4 + i];
            #pragma unroll
            for (int j = 0; j < 4; j++) b[j] = Bs[k][tx * 4 + j];
            #pragma unroll
            for (int i = 0; i < 4; i++)
                #pragma unroll
                for (int j = 0; j < 4; j++)
                    acc[i][j] = fmaf(a[i], b[j], acc[i][j]);
        }
        __syncthreads();
    }

    #pragma unroll
    for (int i = 0; i < 4; i++) {
        int m = bm + ty * 4 + i;
        #pragma unroll
        for (int j = 0; j < 4; j++) {
            int n = bn + tx * 4 + j;
            float v = acc[i][j] + bias[n];
            if (ACT == 1) v = fmaxf(v, 0.0f);
            C[(size_t)m * N + n] = v;
        }
    }
}

// ---------------------------------------------------------------------------
// Flash-style causal attention.
// qkv: [M, 3D] fp32 rows = [q | k | v], head h slice at h*64 within each third.
// Block = (q-tile 64, h, b), 256 threads as 16x16. K/V tiles of 64 staged in
// LDS, online softmax with per-row (m,l) kept in registers (duplicated across
// the 4 64-lane segments). LDS layout (exactly 64 KB, 2 blocks/CU):
//   Qs[i][d^ (i&31)]          row-major, XOR-swizzled scalar reads
//   Ks[d][swz4(j,d)]          dim-major (transposed), float4-group swizzle
//   Vs[j][d]                  row-major, float4 reads
//   Ps[r][c ^ (r&31)]         row-major, XOR-swizzled
// Softmax scratch (redmax/redsum/alpha) aliases Ks rows 0..8 — K is dead
// between the S-GEMM and the next tile's staging (barriers separate).
// ---------------------------------------------------------------------------
__global__ __launch_bounds__(256) void k_attn_flash(const float* __restrict__ qkv,
                                                    float* __restrict__ o)
{
    const int qt  = blockIdx.x;          // 0..15 query tile
    const int h   = blockIdx.y;
    const int b   = blockIdx.z;
    const int tid = threadIdx.x;
    const int tx  = tid & 15, ty = tid >> 4;
    const int q0  = qt * 64;
    const int r   = tid & 63;            // softmax row owned by this thread
    const int seg = tid >> 6;            // 0..3 column segment

    __shared__ float Qs[64][64];
    __shared__ float Ks[64][64];
    __shared__ float Vs[64][64];
    __shared__ float Ps[64][64];
    float* redmax = &Ks[0][0];           // [4*64] transient
    float* redsum = &Ks[4][0];           // [4*64] transient
    float* alv    = &Ks[8][0];           // [64]   transient

    const size_t rstride = 3 * Dn;
    const float* qbase = qkv + (size_t)b * Sn * rstride + h * DKn;

    // stage Q tile (once per block)
    #pragma unroll
    for (int it = 0; it < 16; it++) {
        int lin = tid + it * 256;
        int i = lin >> 6, d = lin & 63;
        Qs[i][d ^ (i & 31)] = qbase[(size_t)(q0 + i) * rstride + d];
    }

    float m_r = -1e30f, l_r = 0.0f;
    float acc[4][4] = {{0.0f}};

    for (int kt = 0; kt <= qt; kt++) {
        const int k0 = kt * 64;
        __syncthreads();   // (A) prior-tile PV / scratch reads done before Ks/Vs overwrite
        #pragma unroll
        for (int it = 0; it < 16; it++) {
            int lin = tid + it * 256;
            int j = lin >> 6, d = lin & 63;
            const float* kvb = qbase + (size_t)(k0 + j) * rstride + d;
            Ks[d][(((j >> 2) ^ (d & 15)) << 2) | (j & 3)] = kvb[Dn];
            Vs[j][d] = kvb[2 * Dn];
        }
        __syncthreads();   // (B)

        // ---- S = Q K^T ----
        float sv[4][4] = {{0.0f}};
        #pragma unroll 4
        for (int k = 0; k < 64; k++) {
            float a0 = Qs[ty * 4 + 0][k ^ ((ty * 4 + 0) & 31)];
            float a1 = Qs[ty * 4 + 1][k ^ ((ty * 4 + 1) & 31)];
            float a2 = Qs[ty * 4 + 2][k ^ ((ty * 4 + 2) & 31)];
            float a3 = Qs[ty * 4 + 3][k ^ ((ty * 4 + 3) & 31)];
            const float4 bb = *(const float4*)&Ks[k][(tx ^ (k & 15)) << 2];
            sv[0][0] = fmaf(a0, bb.x, sv[0][0]); sv[0][1] = fmaf(a0, bb.y, sv[0][1]);
            sv[0][2] = fmaf(a0, bb.z, sv[0][2]); sv[0][3] = fmaf(a0, bb.w, sv[0][3]);
            sv[1][0] = fmaf(a1, bb.x, sv[1][0]); sv[1][1] = fmaf(a1, bb.y, sv[1][1]);
            sv[1][2] = fmaf(a1, bb.z, sv[1][2]); sv[1][3] = fmaf(a1, bb.w, sv[1][3]);
            sv[2][0] = fmaf(a2, bb.x, sv[2][0]); sv[2][1] = fmaf(a2, bb.y, sv[2][1]);
            sv[2][2] = fmaf(a2, bb.z, sv[2][2]); sv[2][3] = fmaf(a2, bb.w, sv[2][3]);
            sv[3][0] = fmaf(a3, bb.x, sv[3][0]); sv[3][1] = fmaf(a3, bb.y, sv[3][1]);
            sv[3][2] = fmaf(a3, bb.z, sv[3][2]); sv[3][3] = fmaf(a3, bb.w, sv[3][3]);
        }

        // scale + causal mask + write P (pre-softmax scores)
        const bool diag = (kt == qt);
        #pragma unroll
        for (int i = 0; i < 4; i++) {
            const int qi = ty * 4 + i;
            #pragma unroll
            for (int j = 0; j < 4; j++) {
                const int kj = tx * 4 + j;
                float v = sv[i][j] * 0.125f;
                if (diag && kj > qi) v = -1e30f;
                Ps[qi][kj ^ (qi & 31)] = v;
            }
        }
        __syncthreads();   // (C)

        // ---- online softmax ----
        float pm = -1e30f;
        #pragma unroll
        for (int j = 0; j < 16; j++)
            pm = fmaxf(pm, Ps[r][(seg * 16 + j) ^ (r & 31)]);
        redmax[seg * 64 + r] = pm;
        __syncthreads();   // (D)

        const float tmax = fmaxf(fmaxf(redmax[r], redmax[64 + r]),
                                 fmaxf(redmax[128 + r], redmax[192 + r]));
        const float m_new = fmaxf(m_r, tmax);
        const float alpha = __expf(m_r - m_new);
        m_r = m_new;
        if (seg == 0) alv[r] = alpha;

        float psum = 0.0f;
        #pragma unroll
        for (int j = 0; j < 16; j++) {
            const int c = (seg * 16 + j) ^ (r & 31);
            const float p = __expf(Ps[r][c] - m_new);
            Ps[r][c] = p;
            psum += p;
        }
        redsum[seg * 64 + r] = psum;
        __syncthreads();   // (E)

        l_r = l_r * alpha + (redsum[r] + redsum[64 + r] + redsum[128 + r] + redsum[192 + r]);

        // rescale accumulator
        #pragma unroll
        for (int i = 0; i < 4; i++) {
            const float al = alv[ty * 4 + i];
            #pragma unroll
            for (int j = 0; j < 4; j++) acc[i][j] *= al;
        }

        // ---- O += P V ----
        #pragma unroll 4
        for (int j = 0; j < 64; j++) {
            const float4 vv = *(const float4*)&Vs[j][tx * 4];
            const float p0 = Ps[ty * 4 + 0][j ^ ((ty * 4 + 0) & 31)];
            const float p1 = Ps[ty * 4 + 1][j ^ ((ty * 4 + 1) & 31)];
            const float p2 = Ps[ty * 4 + 2][j ^ ((ty * 4 + 2) & 31)];
            const float p3 = Ps[ty * 4 + 3][j ^ ((ty * 4 + 3) & 31)];
            acc[0][0] = fmaf(p0, vv.x, acc[0][0]); acc[0][1] = fmaf(p0, vv.y, acc[0][1]);
            acc[0][2] = fmaf(p0, vv.z, acc[0][2]); acc[0][3] = fmaf(p0, vv.w, acc[0][3]);
            acc[1][0] = fmaf(p1, vv.x, acc[1][0]); acc[1][1] = fmaf(p1, vv.y, acc[1][1]);
            acc[1][2] = fmaf(p1, vv.z, acc[1][2]); acc[1][3] = fmaf(p1, vv.w, acc[1][3]);
            acc[2][0] = fmaf(p2, vv.x, acc[2][0]); acc[2][1] = fmaf(p2, vv.y, acc[2][1]);
            acc[2][2] = fmaf(p2, vv.z, acc[2][2]); acc[2][3] = fmaf(p2, vv.w, acc[2][3]);
            acc[3][0] = fmaf(p3, vv.x, acc[3][0]); acc[3][1] = fmaf(p3, vv.y, acc[3][1]);
            acc[3][2] = fmaf(p3, vv.z, acc[3][2]); acc[3][3] = fmaf(p3, vv.w, acc[3][3]);
        }
    }

    __syncthreads();
    if (seg == 0) alv[r] = 1.0f / l_r;   // Ks fully dead now
    __syncthreads();

    #pragma unroll
    for (int i = 0; i < 4; i++) {
        const int qi = ty * 4 + i;
        const float linv = alv[qi];
        float4 outv;
        outv.x = acc[i][0] * linv; outv.y = acc[i][1] * linv;
        outv.z = acc[i][2] * linv; outv.w = acc[i][3] * linv;
        *(float4*)&o[(size_t)(b * Sn + q0 + qi) * Dn + h * DKn + tx * 4] = outv;
    }
}

// ---------------------------------------------------------------------------
// x = LayerNorm(t + x) * g + b   (row = 512 elems, biased var, eps 1e-5)
// ---------------------------------------------------------------------------
__device__ inline float block_reduce_sum(float v, float* red, int tid) {
    red[tid] = v;
    __syncthreads();
    for (int s = 128; s > 0; s >>= 1) {
        if (tid < s) red[tid] += red[tid + s];
        __syncthreads();
    }
    float r = red[0];
    __syncthreads();
    return r;
}

__global__ __launch_bounds__(256) void k_residual_ln(
    const float* __restrict__ t, float* __restrict__ x,
    const float* __restrict__ g, const float* __restrict__ be)
{
    __shared__ float red[256];
    const int row = blockIdx.x, tid = threadIdx.x;
    const size_t base = (size_t)row * Dn;

    float v0 = t[base + tid] + x[base + tid];
    float v1 = t[base + 256 + tid] + x[base + 256 + tid];

    float mean = block_reduce_sum(v0 + v1, red, tid) * (1.0f / Dn);
    float d0 = v0 - mean, d1 = v1 - mean;
    float var = block_reduce_sum(d0 * d0 + d1 * d1, red, tid) * (1.0f / Dn);
    float inv = rsqrtf(var + 1e-5f);

    x[base + tid]       = d0 * inv * g[tid]       + be[tid];
    x[base + 256 + tid] = d1 * inv * g[256 + tid] + be[256 + tid];
}

// ---------------------------------------------------------------------------
// launcher
// ---------------------------------------------------------------------------
extern "C" void kernel_launch(void* const* d_in, const int* in_sizes, int n_in,
                              void* d_out, int out_size, void* d_ws, size_t ws_size,
                              hipStream_t stream)
{
    const float* x_in   = (const float*)d_in[0];
    const float* qkv_w  = (const float*)d_in[1];
    const float* qkv_b  = (const float*)d_in[2];
    const float* out_w  = (const float*)d_in[3];
    const float* out_b  = (const float*)d_in[4];
    const float* ln1_g  = (const float*)d_in[5];
    const float* ln1_b  = (const float*)d_in[6];
    const float* mlp_w1 = (const float*)d_in[7];
    const float* mlp_b1 = (const float*)d_in[8];
    const float* mlp_w2 = (const float*)d_in[9];
    const float* mlp_b2 = (const float*)d_in[10];
    const float* ln2_g  = (const float*)d_in[11];
    const float* ln2_b  = (const float*)d_in[12];

    // workspace layout (fp32): X (16MB) | BUF1 (64MB) | BUF2 (16MB); BUF3 = d_out
    float* X    = (float*)d_ws;
    float* BUF1 = X + (size_t)Mn * Dn;
    float* BUF2 = BUF1 + (size_t)Mn * DFFn;
    float* BUF3 = (float*)d_out;

    const size_t xBytes = (size_t)Mn * Dn * sizeof(float);
    hipMemcpyAsync(X, x_in, xBytes, hipMemcpyDeviceToDevice, stream);

    for (int l = 0; l < Ln; l++) {
        // QKV projection: [M,512] @ [512,1536]
        k_gemm_bias<0><<<dim3((3 * Dn) / 64, Mn / 64), 256, 0, stream>>>(
            X, qkv_w + (size_t)l * Dn * 3 * Dn, qkv_b + (size_t)l * 3 * Dn,
            BUF1, Mn, 3 * Dn, Dn);
        // flash causal attention
        k_attn_flash<<<dim3(Sn / 64, Hn, Bn), 256, 0, stream>>>(BUF1, BUF2);
        // output projection: [M,512] @ [512,512]
        k_gemm_bias<0><<<dim3(Dn / 64, Mn / 64), 256, 0, stream>>>(
            BUF2, out_w + (size_t)l * Dn * Dn, out_b + (size_t)l * Dn,
            BUF3, Mn, Dn, Dn);
        // x = LN(proj + x)
        k_residual_ln<<<Mn, 256, 0, stream>>>(BUF3, X, ln1_g + (size_t)l * Dn, ln1_b + (size_t)l * Dn);
        // MLP up + ReLU: [M,512] @ [512,2048]
        k_gemm_bias<1><<<dim3(DFFn / 64, Mn / 64), 256, 0, stream>>>(
            X, mlp_w1 + (size_t)l * Dn * DFFn, mlp_b1 + (size_t)l * DFFn,
            BUF1, Mn, DFFn, Dn);
        // MLP down: [M,2048] @ [2048,512]
        k_gemm_bias<0><<<dim3(Dn / 64, Mn / 64), 256, 0, stream>>>(
            BUF1, mlp_w2 + (size_t)l * DFFn * Dn, mlp_b2 + (size_t)l * Dn,
            BUF3, Mn, Dn, DFFn);
        // x = LN(x + mlp)
        k_residual_ln<<<Mn, 256, 0, stream>>>(BUF3, X, ln2_g + (size_t)l * Dn, ln2_b + (size_t)l * Dn);
    }

    hipMemcpyAsync(d_out, X, xBytes, hipMemcpyDeviceToDevice, stream);
}

// Round 4
// 3419.744 us; speedup vs baseline: 4.4254x; 2.1122x over previous
//
#include <hip/hip_runtime.h>
#include <math.h>

// Problem constants
#define Bn   8
#define Sn   1024
#define Dn   512
#define Hn   8
#define DKn  64
#define Ln   6
#define DFFn 2048
#define Mn   (Bn * Sn)   // 8192 rows

typedef __bf16 bf16x8 __attribute__((ext_vector_type(8)));
typedef float  f32x4  __attribute__((ext_vector_type(4)));

// async global->LDS, 16B per lane. LDS dest must be wave-uniform base + lane*16.
__device__ __forceinline__ void gl_lds16(const void* g, void* l) {
    __builtin_amdgcn_global_load_lds(
        (const __attribute__((address_space(1))) void*)g,
        (__attribute__((address_space(3))) void*)l, 16, 0, 0);
}

// ---------------------------------------------------------------------------
// fp32 -> bf16 cast
// ---------------------------------------------------------------------------
__global__ __launch_bounds__(256) void k_cast_bf16(const float* __restrict__ in,
                                                   __bf16* __restrict__ out, int n) {
    int i = blockIdx.x * 256 + threadIdx.x;
    if (i < n) out[i] = (__bf16)in[i];
}

// ---------------------------------------------------------------------------
// W[K][N] fp32  ->  Wt[N][K] bf16   (LDS-tiled transpose, 32x32 tiles)
// ---------------------------------------------------------------------------
__global__ __launch_bounds__(256) void k_trans_cast(
    const float* __restrict__ in, __bf16* __restrict__ out, int K, int N)
{
    __shared__ float t[32][33];
    const int n0 = blockIdx.x * 32, k0 = blockIdx.y * 32;
    const int tx = threadIdx.x, ty = threadIdx.y;   // 32 x 8
    #pragma unroll
    for (int r = 0; r < 4; r++)
        t[ty + 8 * r][tx] = in[(size_t)(k0 + ty + 8 * r) * N + n0 + tx];
    __syncthreads();
    #pragma unroll
    for (int r = 0; r < 4; r++)
        out[(size_t)(n0 + ty + 8 * r) * K + k0 + tx] = (__bf16)t[tx][ty + 8 * r];
}

// ---------------------------------------------------------------------------
// MFMA GEMM: C[M,N] = act(A[M,K]bf16 @ Bt[N,K]bf16^T + bias[N]fp32)
// Block: 256 thr = 4 waves (2x2). Tile: 128 x (JT*32). BK=32.
// Each wave: 4 x JT tiles of 16x16 via v_mfma_f32_16x16x32_bf16.
// A/B fragment: elem[j] = X[lane&15][ (lane>>4)*8 + j ]  (m97-verified)
// C/D: col = lane&15, row = (lane>>4)*4 + reg            (m89/m91-verified)
// ---------------------------------------------------------------------------
template <int RELU, int OUTBF, int JT>
__global__ __launch_bounds__(256) void k_gemm_mfma(
    const __bf16* __restrict__ A, const __bf16* __restrict__ Bt,
    const float* __restrict__ bias, void* __restrict__ Cout,
    int M, int N, int K)
{
    constexpr int BN = JT * 32;   // 128 or 64
    __shared__ __bf16 As[128][32];
    __shared__ __bf16 Bs[BN][32];
    const int tid  = threadIdx.x;
    const int lane = tid & 63;
    const int wave = tid >> 6;
    const int wy   = wave >> 1, wx = wave & 1;
    const int m16  = lane & 15, quad = lane >> 4;
    const int bm   = blockIdx.y * 128, bn = blockIdx.x * BN;

    f32x4 acc[4][JT];
    #pragma unroll
    for (int i = 0; i < 4; i++)
        #pragma unroll
        for (int j = 0; j < JT; j++)
            acc[i][j] = (f32x4){0.f, 0.f, 0.f, 0.f};

    const __bf16* Ap = A  + (size_t)bm * K;
    const __bf16* Bp = Bt + (size_t)bn * K;

    for (int k0 = 0; k0 < K; k0 += 32) {
        __syncthreads();   // prior-iter LDS reads done
        #pragma unroll
        for (int c = 0; c < 2; c++) {           // A: 128x32 bf16 = 512 x 16B
            int lin = tid + c * 256;
            int row = lin >> 2, kc = (lin & 3) << 3;
            gl_lds16(Ap + (size_t)row * K + k0 + kc, (void*)(&As[0][0] + lin * 8));
        }
        #pragma unroll
        for (int c = 0; c < JT / 2; c++) {      // B: BNx32 bf16
            int lin = tid + c * 256;
            int row = lin >> 2, kc = (lin & 3) << 3;
            gl_lds16(Bp + (size_t)row * K + k0 + kc, (void*)(&Bs[0][0] + lin * 8));
        }
        __syncthreads();   // drains vmcnt (global_load_lds) per barrier semantics

        bf16x8 af[4], bfr[JT];
        #pragma unroll
        for (int i = 0; i < 4; i++)
            af[i] = *(const bf16x8*)&As[wy * 64 + i * 16 + m16][quad * 8];
        #pragma unroll
        for (int j = 0; j < JT; j++)
            bfr[j] = *(const bf16x8*)&Bs[wx * JT * 16 + j * 16 + m16][quad * 8];
        #pragma unroll
        for (int i = 0; i < 4; i++)
            #pragma unroll
            for (int j = 0; j < JT; j++)
                acc[i][j] = __builtin_amdgcn_mfma_f32_16x16x32_bf16(
                    af[i], bfr[j], acc[i][j], 0, 0, 0);
    }

    float*  Cf = (float*)Cout;
    __bf16* Cb = (__bf16*)Cout;
    #pragma unroll
    for (int i = 0; i < 4; i++) {
        const int row0 = bm + wy * 64 + i * 16 + quad * 4;
        #pragma unroll
        for (int j = 0; j < JT; j++) {
            const int col = bn + wx * JT * 16 + j * 16 + m16;
            const float bv = bias[col];
            #pragma unroll
            for (int r = 0; r < 4; r++) {
                float v = acc[i][j][r] + bv;
                if (RELU) v = fmaxf(v, 0.f);
                if (OUTBF) Cb[(size_t)(row0 + r) * N + col] = (__bf16)v;
                else       Cf[(size_t)(row0 + r) * N + col] = v;
            }
        }
    }
}

// ---------------------------------------------------------------------------
// Flash-style causal attention (fp32 compute, bf16 in/out).
// qkv: [M, 3D] bf16 rows = [q | k | v]. Block = (q-tile 64, h, b), 256 thr.
// ---------------------------------------------------------------------------
__global__ __launch_bounds__(256) void k_attn_flash(const __bf16* __restrict__ qkv,
                                                    __bf16* __restrict__ o)
{
    const int qt  = blockIdx.x;
    const int h   = blockIdx.y;
    const int b   = blockIdx.z;
    const int tid = threadIdx.x;
    const int tx  = tid & 15, ty = tid >> 4;
    const int q0  = qt * 64;
    const int r   = tid & 63;
    const int seg = tid >> 6;

    __shared__ float Qs[64][64];
    __shared__ float Ks[64][64];
    __shared__ float Vs[64][64];
    __shared__ float Ps[64][64];
    float* redmax = &Ks[0][0];
    float* redsum = &Ks[4][0];
    float* alv    = &Ks[8][0];

    const size_t rstride = 3 * Dn;
    const __bf16* qbase = qkv + (size_t)b * Sn * rstride + h * DKn;

    #pragma unroll
    for (int it = 0; it < 16; it++) {
        int lin = tid + it * 256;
        int i = lin >> 6, d = lin & 63;
        Qs[i][d ^ (i & 31)] = (float)qbase[(size_t)(q0 + i) * rstride + d];
    }

    float m_r = -1e30f, l_r = 0.0f;
    float acc[4][4] = {{0.0f}};

    for (int kt = 0; kt <= qt; kt++) {
        const int k0 = kt * 64;
        __syncthreads();   // (A)
        #pragma unroll
        for (int it = 0; it < 16; it++) {
            int lin = tid + it * 256;
            int j = lin >> 6, d = lin & 63;
            const __bf16* kvb = qbase + (size_t)(k0 + j) * rstride + d;
            Ks[d][(((j >> 2) ^ (d & 15)) << 2) | (j & 3)] = (float)kvb[Dn];
            Vs[j][d] = (float)kvb[2 * Dn];
        }
        __syncthreads();   // (B)

        // ---- S = Q K^T ----
        float sv[4][4] = {{0.0f}};
        #pragma unroll 4
        for (int k = 0; k < 64; k++) {
            float a0 = Qs[ty * 4 + 0][k ^ ((ty * 4 + 0) & 31)];
            float a1 = Qs[ty * 4 + 1][k ^ ((ty * 4 + 1) & 31)];
            float a2 = Qs[ty * 4 + 2][k ^ ((ty * 4 + 2) & 31)];
            float a3 = Qs[ty * 4 + 3][k ^ ((ty * 4 + 3) & 31)];
            const float4 bb = *(const float4*)&Ks[k][(tx ^ (k & 15)) << 2];
            sv[0][0] = fmaf(a0, bb.x, sv[0][0]); sv[0][1] = fmaf(a0, bb.y, sv[0][1]);
            sv[0][2] = fmaf(a0, bb.z, sv[0][2]); sv[0][3] = fmaf(a0, bb.w, sv[0][3]);
            sv[1][0] = fmaf(a1, bb.x, sv[1][0]); sv[1][1] = fmaf(a1, bb.y, sv[1][1]);
            sv[1][2] = fmaf(a1, bb.z, sv[1][2]); sv[1][3] = fmaf(a1, bb.w, sv[1][3]);
            sv[2][0] = fmaf(a2, bb.x, sv[2][0]); sv[2][1] = fmaf(a2, bb.y, sv[2][1]);
            sv[2][2] = fmaf(a2, bb.z, sv[2][2]); sv[2][3] = fmaf(a2, bb.w, sv[2][3]);
            sv[3][0] = fmaf(a3, bb.x, sv[3][0]); sv[3][1] = fmaf(a3, bb.y, sv[3][1]);
            sv[3][2] = fmaf(a3, bb.z, sv[3][2]); sv[3][3] = fmaf(a3, bb.w, sv[3][3]);
        }

        const bool diag = (kt == qt);
        #pragma unroll
        for (int i = 0; i < 4; i++) {
            const int qi = ty * 4 + i;
            #pragma unroll
            for (int j = 0; j < 4; j++) {
                const int kj = tx * 4 + j;
                float v = sv[i][j] * 0.125f;
                if (diag && kj > qi) v = -1e30f;
                Ps[qi][kj ^ (qi & 31)] = v;
            }
        }
        __syncthreads();   // (C)

        float pm = -1e30f;
        #pragma unroll
        for (int j = 0; j < 16; j++)
            pm = fmaxf(pm, Ps[r][(seg * 16 + j) ^ (r & 31)]);
        redmax[seg * 64 + r] = pm;
        __syncthreads();   // (D)

        const float tmax = fmaxf(fmaxf(redmax[r], redmax[64 + r]),
                                 fmaxf(redmax[128 + r], redmax[192 + r]));
        const float m_new = fmaxf(m_r, tmax);
        const float alpha = __expf(m_r - m_new);
        m_r = m_new;
        if (seg == 0) alv[r] = alpha;

        float psum = 0.0f;
        #pragma unroll
        for (int j = 0; j < 16; j++) {
            const int c = (seg * 16 + j) ^ (r & 31);
            const float p = __expf(Ps[r][c] - m_new);
            Ps[r][c] = p;
            psum += p;
        }
        redsum[seg * 64 + r] = psum;
        __syncthreads();   // (E)

        l_r = l_r * alpha + (redsum[r] + redsum[64 + r] + redsum[128 + r] + redsum[192 + r]);

        #pragma unroll
        for (int i = 0; i < 4; i++) {
            const float al = alv[ty * 4 + i];
            #pragma unroll
            for (int j = 0; j < 4; j++) acc[i][j] *= al;
        }

        #pragma unroll 4
        for (int j = 0; j < 64; j++) {
            const float4 vv = *(const float4*)&Vs[j][tx * 4];
            const float p0 = Ps[ty * 4 + 0][j ^ ((ty * 4 + 0) & 31)];
            const float p1 = Ps[ty * 4 + 1][j ^ ((ty * 4 + 1) & 31)];
            const float p2 = Ps[ty * 4 + 2][j ^ ((ty * 4 + 2) & 31)];
            const float p3 = Ps[ty * 4 + 3][j ^ ((ty * 4 + 3) & 31)];
            acc[0][0] = fmaf(p0, vv.x, acc[0][0]); acc[0][1] = fmaf(p0, vv.y, acc[0][1]);
            acc[0][2] = fmaf(p0, vv.z, acc[0][2]); acc[0][3] = fmaf(p0, vv.w, acc[0][3]);
            acc[1][0] = fmaf(p1, vv.x, acc[1][0]); acc[1][1] = fmaf(p1, vv.y, acc[1][1]);
            acc[1][2] = fmaf(p1, vv.z, acc[1][2]); acc[1][3] = fmaf(p1, vv.w, acc[1][3]);
            acc[2][0] = fmaf(p2, vv.x, acc[2][0]); acc[2][1] = fmaf(p2, vv.y, acc[2][1]);
            acc[2][2] = fmaf(p2, vv.z, acc[2][2]); acc[2][3] = fmaf(p2, vv.w, acc[2][3]);
            acc[3][0] = fmaf(p3, vv.x, acc[3][0]); acc[3][1] = fmaf(p3, vv.y, acc[3][1]);
            acc[3][2] = fmaf(p3, vv.z, acc[3][2]); acc[3][3] = fmaf(p3, vv.w, acc[3][3]);
        }
    }

    __syncthreads();
    if (seg == 0) alv[r] = 1.0f / l_r;
    __syncthreads();

    #pragma unroll
    for (int i = 0; i < 4; i++) {
        const int qi = ty * 4 + i;
        const float linv = alv[qi];
        __bf16* orow = o + (size_t)(b * Sn + q0 + qi) * Dn + h * DKn + tx * 4;
        #pragma unroll
        for (int c = 0; c < 4; c++) orow[c] = (__bf16)(acc[i][c] * linv);
    }
}

// ---------------------------------------------------------------------------
// x = LayerNorm(t + x); writes fp32 x and bf16 copy xb.
// ---------------------------------------------------------------------------
__device__ inline float block_reduce_sum(float v, float* red, int tid) {
    red[tid] = v;
    __syncthreads();
    for (int s = 128; s > 0; s >>= 1) {
        if (tid < s) red[tid] += red[tid + s];
        __syncthreads();
    }
    float r = red[0];
    __syncthreads();
    return r;
}

__global__ __launch_bounds__(256) void k_residual_ln(
    const float* __restrict__ t, float* __restrict__ x, __bf16* __restrict__ xb,
    const float* __restrict__ g, const float* __restrict__ be)
{
    __shared__ float red[256];
    const int row = blockIdx.x, tid = threadIdx.x;
    const size_t base = (size_t)row * Dn;

    float v0 = t[base + tid] + x[base + tid];
    float v1 = t[base + 256 + tid] + x[base + 256 + tid];

    float mean = block_reduce_sum(v0 + v1, red, tid) * (1.0f / Dn);
    float d0 = v0 - mean, d1 = v1 - mean;
    float var = block_reduce_sum(d0 * d0 + d1 * d1, red, tid) * (1.0f / Dn);
    float inv = rsqrtf(var + 1e-5f);

    float o0 = d0 * inv * g[tid]       + be[tid];
    float o1 = d1 * inv * g[256 + tid] + be[256 + tid];
    x[base + tid]        = o0;
    x[base + 256 + tid]  = o1;
    xb[base + tid]       = (__bf16)o0;
    xb[base + 256 + tid] = (__bf16)o1;
}

// ---------------------------------------------------------------------------
// launcher
// ---------------------------------------------------------------------------
extern "C" void kernel_launch(void* const* d_in, const int* in_sizes, int n_in,
                              void* d_out, int out_size, void* d_ws, size_t ws_size,
                              hipStream_t stream)
{
    const float* x_in   = (const float*)d_in[0];
    const float* qkv_w  = (const float*)d_in[1];
    const float* qkv_b  = (const float*)d_in[2];
    const float* out_w  = (const float*)d_in[3];
    const float* out_b  = (const float*)d_in[4];
    const float* ln1_g  = (const float*)d_in[5];
    const float* ln1_b  = (const float*)d_in[6];
    const float* mlp_w1 = (const float*)d_in[7];
    const float* mlp_b1 = (const float*)d_in[8];
    const float* mlp_w2 = (const float*)d_in[9];
    const float* mlp_b2 = (const float*)d_in[10];
    const float* ln2_g  = (const float*)d_in[11];
    const float* ln2_b  = (const float*)d_in[12];

    // workspace layout (~94 MB)
    char* p = (char*)d_ws;
    float*  X    = (float*)p;  p += (size_t)Mn * Dn * 4;        // 16 MB fp32 residual
    __bf16* Xb   = (__bf16*)p; p += (size_t)Mn * Dn * 2;        //  8 MB bf16 x
    __bf16* QKVb = (__bf16*)p; p += (size_t)Mn * 3 * Dn * 2;    // 24 MB
    __bf16* AOb  = (__bf16*)p; p += (size_t)Mn * Dn * 2;        //  8 MB attn out
    __bf16* Hb   = (__bf16*)p; p += (size_t)Mn * DFFn * 2;      // 32 MB mlp hidden
    __bf16* Wq   = (__bf16*)p; p += (size_t)3 * Dn * Dn * 2;    // 1.5 MB  [1536][512]
    __bf16* Wo   = (__bf16*)p; p += (size_t)Dn * Dn * 2;        // 0.5 MB  [512][512]
    __bf16* W1   = (__bf16*)p; p += (size_t)DFFn * Dn * 2;      // 2 MB    [2048][512]
    __bf16* W2   = (__bf16*)p; p += (size_t)Dn * DFFn * 2;      // 2 MB    [512][2048]
    float* BUF3 = (float*)d_out;   // pre-LN temp lives in d_out

    const size_t xBytes = (size_t)Mn * Dn * sizeof(float);
    hipMemcpyAsync(X, x_in, xBytes, hipMemcpyDeviceToDevice, stream);
    k_cast_bf16<<<(Mn * Dn) / 256, 256, 0, stream>>>(x_in, Xb, Mn * Dn);

    for (int l = 0; l < Ln; l++) {
        // weight transpose+cast for this layer
        k_trans_cast<<<dim3(1536 / 32, 512 / 32), dim3(32, 8), 0, stream>>>(
            qkv_w + (size_t)l * Dn * 3 * Dn, Wq, Dn, 3 * Dn);
        k_trans_cast<<<dim3(512 / 32, 512 / 32), dim3(32, 8), 0, stream>>>(
            out_w + (size_t)l * Dn * Dn, Wo, Dn, Dn);
        k_trans_cast<<<dim3(2048 / 32, 512 / 32), dim3(32, 8), 0, stream>>>(
            mlp_w1 + (size_t)l * Dn * DFFn, W1, Dn, DFFn);
        k_trans_cast<<<dim3(512 / 32, 2048 / 32), dim3(32, 8), 0, stream>>>(
            mlp_w2 + (size_t)l * DFFn * Dn, W2, DFFn, Dn);

        // QKV projection -> bf16 [M,1536]
        k_gemm_mfma<0, 1, 4><<<dim3(12, 64), 256, 0, stream>>>(
            Xb, Wq, qkv_b + (size_t)l * 3 * Dn, QKVb, Mn, 3 * Dn, Dn);
        // flash causal attention -> bf16 [M,512]
        k_attn_flash<<<dim3(Sn / 64, Hn, Bn), 256, 0, stream>>>(QKVb, AOb);
        // output projection -> fp32 BUF3
        k_gemm_mfma<0, 0, 2><<<dim3(8, 64), 256, 0, stream>>>(
            AOb, Wo, out_b + (size_t)l * Dn, BUF3, Mn, Dn, Dn);
        // x = LN(proj + x)
        k_residual_ln<<<Mn, 256, 0, stream>>>(BUF3, X, Xb,
            ln1_g + (size_t)l * Dn, ln1_b + (size_t)l * Dn);
        // MLP up + ReLU -> bf16 [M,2048]
        k_gemm_mfma<1, 1, 4><<<dim3(16, 64), 256, 0, stream>>>(
            Xb, W1, mlp_b1 + (size_t)l * DFFn, Hb, Mn, DFFn, Dn);
        // MLP down -> fp32 BUF3
        k_gemm_mfma<0, 0, 2><<<dim3(8, 64), 256, 0, stream>>>(
            Hb, W2, mlp_b2 + (size_t)l * Dn, BUF3, Mn, Dn, DFFn);
        // x = LN(x + mlp)
        k_residual_ln<<<Mn, 256, 0, stream>>>(BUF3, X, Xb,
            ln2_g + (size_t)l * Dn, ln2_b + (size_t)l * Dn);
    }

    hipMemcpyAsync(d_out, X, xBytes, hipMemcpyDeviceToDevice, stream);
}

// Round 5
// 1488.306 us; speedup vs baseline: 10.1685x; 2.2977x over previous
//
#include <hip/hip_runtime.h>
#include <math.h>

// Problem constants
#define Bn   8
#define Sn   1024
#define Dn   512
#define Hn   8
#define DKn  64
#define Ln   6
#define DFFn 2048
#define Mn   (Bn * Sn)   // 8192 rows

typedef __bf16 bf16x8 __attribute__((ext_vector_type(8)));
typedef float  f32x4  __attribute__((ext_vector_type(4)));

// async global->LDS, 16B per lane. LDS dest must be wave-uniform base + lane*16.
__device__ __forceinline__ void gl_lds16(const void* g, void* l) {
    __builtin_amdgcn_global_load_lds(
        (const __attribute__((address_space(1))) void*)g,
        (__attribute__((address_space(3))) void*)l, 16, 0, 0);
}

// ---------------------------------------------------------------------------
// fp32 -> bf16 cast
// ---------------------------------------------------------------------------
__global__ __launch_bounds__(256) void k_cast_bf16(const float* __restrict__ in,
                                                   __bf16* __restrict__ out, int n) {
    int i = blockIdx.x * 256 + threadIdx.x;
    if (i < n) out[i] = (__bf16)in[i];
}

// ---------------------------------------------------------------------------
// W[K][N] fp32  ->  Wt[N][K] bf16   (LDS-tiled transpose, 32x32 tiles)
// ---------------------------------------------------------------------------
__global__ __launch_bounds__(256) void k_trans_cast(
    const float* __restrict__ in, __bf16* __restrict__ out, int K, int N)
{
    __shared__ float t[32][33];
    const int n0 = blockIdx.x * 32, k0 = blockIdx.y * 32;
    const int tx = threadIdx.x, ty = threadIdx.y;   // 32 x 8
    #pragma unroll
    for (int r = 0; r < 4; r++)
        t[ty + 8 * r][tx] = in[(size_t)(k0 + ty + 8 * r) * N + n0 + tx];
    __syncthreads();
    #pragma unroll
    for (int r = 0; r < 4; r++)
        out[(size_t)(n0 + ty + 8 * r) * K + k0 + tx] = (__bf16)t[tx][ty + 8 * r];
}

// ---------------------------------------------------------------------------
// V slice of QKV [M][1536] (V at col 1024 + h*64 + d)  ->  Vt[b*8+h][d][s] bf16
// ---------------------------------------------------------------------------
__global__ __launch_bounds__(256) void k_trans_v(
    const __bf16* __restrict__ qkv, __bf16* __restrict__ Vt)
{
    __shared__ float t[32][33];
    const int s0 = blockIdx.x * 32;
    const int d0 = blockIdx.y * 32;
    const int bh = blockIdx.z;
    const int b = bh >> 3, h = bh & 7;
    const int tx = threadIdx.x, ty = threadIdx.y;   // 32 x 8
    const __bf16* src = qkv + (size_t)b * Sn * 1536 + 1024 + h * DKn;
    #pragma unroll
    for (int r = 0; r < 4; r++)
        t[ty + 8 * r][tx] = (float)src[(size_t)(s0 + ty + 8 * r) * 1536 + d0 + tx];
    __syncthreads();
    #pragma unroll
    for (int r = 0; r < 4; r++)
        Vt[((size_t)bh * DKn + d0 + ty + 8 * r) * Sn + s0 + tx] = (__bf16)t[tx][ty + 8 * r];
}

// ---------------------------------------------------------------------------
// MFMA GEMM: C[M,N] = act(A[M,K]bf16 @ Bt[N,K]bf16^T + bias[N]fp32)
// Block: 256 thr = 4 waves (2x2). Tile: 128 x (JT*32). BK=32.
// A/B fragment: elem[j] = X[lane&15][ (lane>>4)*8 + j ]  (m97-verified)
// C/D: col = lane&15, row = (lane>>4)*4 + reg            (m89/m91-verified)
// ---------------------------------------------------------------------------
template <int RELU, int OUTBF, int JT>
__global__ __launch_bounds__(256) void k_gemm_mfma(
    const __bf16* __restrict__ A, const __bf16* __restrict__ Bt,
    const float* __restrict__ bias, void* __restrict__ Cout,
    int M, int N, int K)
{
    constexpr int BN = JT * 32;   // 128 or 64
    __shared__ __bf16 As[128][32];
    __shared__ __bf16 Bs[BN][32];
    const int tid  = threadIdx.x;
    const int lane = tid & 63;
    const int wave = tid >> 6;
    const int wy   = wave >> 1, wx = wave & 1;
    const int m16  = lane & 15, quad = lane >> 4;
    const int bm   = blockIdx.y * 128, bn = blockIdx.x * BN;

    f32x4 acc[4][JT];
    #pragma unroll
    for (int i = 0; i < 4; i++)
        #pragma unroll
        for (int j = 0; j < JT; j++)
            acc[i][j] = (f32x4){0.f, 0.f, 0.f, 0.f};

    const __bf16* Ap = A  + (size_t)bm * K;
    const __bf16* Bp = Bt + (size_t)bn * K;

    for (int k0 = 0; k0 < K; k0 += 32) {
        __syncthreads();
        #pragma unroll
        for (int c = 0; c < 2; c++) {           // A: 128x32 bf16 = 512 x 16B
            int lin = tid + c * 256;
            int row = lin >> 2, kc = (lin & 3) << 3;
            gl_lds16(Ap + (size_t)row * K + k0 + kc, (void*)(&As[0][0] + lin * 8));
        }
        #pragma unroll
        for (int c = 0; c < JT / 2; c++) {      // B: BNx32 bf16
            int lin = tid + c * 256;
            int row = lin >> 2, kc = (lin & 3) << 3;
            gl_lds16(Bp + (size_t)row * K + k0 + kc, (void*)(&Bs[0][0] + lin * 8));
        }
        __syncthreads();

        bf16x8 af[4], bfr[JT];
        #pragma unroll
        for (int i = 0; i < 4; i++)
            af[i] = *(const bf16x8*)&As[wy * 64 + i * 16 + m16][quad * 8];
        #pragma unroll
        for (int j = 0; j < JT; j++)
            bfr[j] = *(const bf16x8*)&Bs[wx * JT * 16 + j * 16 + m16][quad * 8];
        #pragma unroll
        for (int i = 0; i < 4; i++)
            #pragma unroll
            for (int j = 0; j < JT; j++)
                acc[i][j] = __builtin_amdgcn_mfma_f32_16x16x32_bf16(
                    af[i], bfr[j], acc[i][j], 0, 0, 0);
    }

    float*  Cf = (float*)Cout;
    __bf16* Cb = (__bf16*)Cout;
    #pragma unroll
    for (int i = 0; i < 4; i++) {
        const int row0 = bm + wy * 64 + i * 16 + quad * 4;
        #pragma unroll
        for (int j = 0; j < JT; j++) {
            const int col = bn + wx * JT * 16 + j * 16 + m16;
            const float bv = bias[col];
            #pragma unroll
            for (int r = 0; r < 4; r++) {
                float v = acc[i][j][r] + bv;
                if (RELU) v = fmaxf(v, 0.f);
                if (OUTBF) Cb[(size_t)(row0 + r) * N + col] = (__bf16)v;
                else       Cf[(size_t)(row0 + r) * N + col] = v;
            }
        }
    }
}

// ---------------------------------------------------------------------------
// MFMA flash attention (causal).
// qkv: [M][1536] bf16 = [q|k|v] per token; Vt: [b*8+h][64][1024] bf16.
// Block = (q-tile 64, h, b), 256 thr = 4 waves; wave w owns q-rows w*16..+15.
// S = Q K^T via 16x16x32 MFMA (K rows are already B^T form).
// Online softmax in registers (C/D rows live in 16-lane groups -> shfl_xor).
// P -> LDS (bf16, A-layout) -> PV MFMA with Vt rows as B^T.
// LDS rows padded to 72 bf16 (144 B): 16B-aligned, 2-way conflicts max (free).
// ---------------------------------------------------------------------------
__global__ __launch_bounds__(256) void k_attn_mfma(
    const __bf16* __restrict__ qkv, const __bf16* __restrict__ Vt,
    __bf16* __restrict__ o)
{
    const int qt  = blockIdx.x;
    const int h   = blockIdx.y;
    const int b   = blockIdx.z;
    const int tid  = threadIdx.x;
    const int lane = tid & 63, wave = tid >> 6;
    const int m16  = lane & 15, quad = lane >> 4;
    const int q0   = qt * 64;

    __shared__ __bf16 Ks[64][72];
    __shared__ __bf16 Vs[64][72];
    __shared__ __bf16 Ps[64][72];

    const __bf16* base = qkv + (size_t)b * Sn * 1536 + h * DKn;      // Q at +0, K at +512
    const __bf16* vtb  = Vt + (size_t)(b * Hn + h) * DKn * Sn;

    // Q fragments (A-operand): rows q0 + wave*16 + m16
    bf16x8 qf[2];
    {
        const __bf16* qrow = base + (size_t)(q0 + wave * 16 + m16) * 1536;
        qf[0] = *(const bf16x8*)(qrow + quad * 8);
        qf[1] = *(const bf16x8*)(qrow + 32 + quad * 8);
    }

    float mrow[4], lrow[4];
    #pragma unroll
    for (int r = 0; r < 4; r++) { mrow[r] = -1e30f; lrow[r] = 0.f; }
    f32x4 acc[4];
    #pragma unroll
    for (int j = 0; j < 4; j++) acc[j] = (f32x4){0.f, 0.f, 0.f, 0.f};

    for (int kt = 0; kt <= qt; kt++) {
        const int k0 = kt * 64;
        __syncthreads();   // prior-iter Ks/Vs reads complete
        #pragma unroll
        for (int it = 0; it < 2; it++) {       // stage K (8 KB) + V (8 KB)
            int lin = tid + it * 256;
            int row = lin >> 3, c8 = (lin & 7) * 8;
            *(bf16x8*)&Ks[row][c8] =
                *(const bf16x8*)(base + (size_t)(k0 + row) * 1536 + 512 + c8);
            *(bf16x8*)&Vs[row][c8] =
                *(const bf16x8*)(vtb + (size_t)row * Sn + k0 + c8);
        }
        __syncthreads();

        // ---- S = Q K^T ----  (4 col-tiles of 16 keys)
        f32x4 sv[4];
        #pragma unroll
        for (int j = 0; j < 4; j++) {
            bf16x8 kf0 = *(const bf16x8*)&Ks[j * 16 + m16][quad * 8];
            bf16x8 kf1 = *(const bf16x8*)&Ks[j * 16 + m16][32 + quad * 8];
            f32x4 s = (f32x4){0.f, 0.f, 0.f, 0.f};
            s = __builtin_amdgcn_mfma_f32_16x16x32_bf16(qf[0], kf0, s, 0, 0, 0);
            s = __builtin_amdgcn_mfma_f32_16x16x32_bf16(qf[1], kf1, s, 0, 0, 0);
            sv[j] = s;
        }

        // scale + causal mask
        const bool diag = (kt == qt);
        #pragma unroll
        for (int j = 0; j < 4; j++)
            #pragma unroll
            for (int r = 0; r < 4; r++) {
                float v = sv[j][r] * 0.125f;
                if (diag && (j * 16 + m16) > (wave * 16 + quad * 4 + r)) v = -1e30f;
                sv[j][r] = v;
            }

        // ---- online softmax (rows = quad*4+r, replicated across 16-lane group) ----
        float pm[4];
        #pragma unroll
        for (int r = 0; r < 4; r++)
            pm[r] = fmaxf(fmaxf(sv[0][r], sv[1][r]), fmaxf(sv[2][r], sv[3][r]));
        #pragma unroll
        for (int off = 1; off < 16; off <<= 1)
            #pragma unroll
            for (int r = 0; r < 4; r++)
                pm[r] = fmaxf(pm[r], __shfl_xor(pm[r], off, 16));

        float al[4];
        #pragma unroll
        for (int r = 0; r < 4; r++) {
            float mn = fmaxf(mrow[r], pm[r]);
            al[r] = __expf(mrow[r] - mn);
            mrow[r] = mn;
        }

        float rs[4] = {0.f, 0.f, 0.f, 0.f};
        #pragma unroll
        for (int j = 0; j < 4; j++)
            #pragma unroll
            for (int r = 0; r < 4; r++) {
                float p = __expf(sv[j][r] - mrow[r]);
                rs[r] += p;
                Ps[wave * 16 + quad * 4 + r][j * 16 + m16] = (__bf16)p;
            }
        #pragma unroll
        for (int off = 1; off < 16; off <<= 1)
            #pragma unroll
            for (int r = 0; r < 4; r++)
                rs[r] += __shfl_xor(rs[r], off, 16);
        #pragma unroll
        for (int r = 0; r < 4; r++) lrow[r] = lrow[r] * al[r] + rs[r];

        // rescale O accumulator (same row mapping as S)
        #pragma unroll
        for (int j = 0; j < 4; j++)
            #pragma unroll
            for (int r = 0; r < 4; r++) acc[j][r] *= al[r];

        // ---- O += P V ----  (P rows written/read by same wave: in-order DS)
        bf16x8 pf0 = *(const bf16x8*)&Ps[wave * 16 + m16][quad * 8];
        bf16x8 pf1 = *(const bf16x8*)&Ps[wave * 16 + m16][32 + quad * 8];
        #pragma unroll
        for (int jd = 0; jd < 4; jd++) {
            bf16x8 vf0 = *(const bf16x8*)&Vs[jd * 16 + m16][quad * 8];
            bf16x8 vf1 = *(const bf16x8*)&Vs[jd * 16 + m16][32 + quad * 8];
            acc[jd] = __builtin_amdgcn_mfma_f32_16x16x32_bf16(pf0, vf0, acc[jd], 0, 0, 0);
            acc[jd] = __builtin_amdgcn_mfma_f32_16x16x32_bf16(pf1, vf1, acc[jd], 0, 0, 0);
        }
    }

    // epilogue: O / l
    #pragma unroll
    for (int r = 0; r < 4; r++) lrow[r] = 1.0f / lrow[r];
    #pragma unroll
    for (int jd = 0; jd < 4; jd++) {
        #pragma unroll
        for (int r = 0; r < 4; r++) {
            const int row = b * Sn + q0 + wave * 16 + quad * 4 + r;
            o[(size_t)row * Dn + h * DKn + jd * 16 + m16] = (__bf16)(acc[jd][r] * lrow[r]);
        }
    }
}

// ---------------------------------------------------------------------------
// x = LayerNorm(t + x); writes fp32 x and bf16 copy xb.
// ---------------------------------------------------------------------------
__device__ inline float block_reduce_sum(float v, float* red, int tid) {
    red[tid] = v;
    __syncthreads();
    for (int s = 128; s > 0; s >>= 1) {
        if (tid < s) red[tid] += red[tid + s];
        __syncthreads();
    }
    float r = red[0];
    __syncthreads();
    return r;
}

__global__ __launch_bounds__(256) void k_residual_ln(
    const float* __restrict__ t, float* __restrict__ x, __bf16* __restrict__ xb,
    const float* __restrict__ g, const float* __restrict__ be)
{
    __shared__ float red[256];
    const int row = blockIdx.x, tid = threadIdx.x;
    const size_t base = (size_t)row * Dn;

    float v0 = t[base + tid] + x[base + tid];
    float v1 = t[base + 256 + tid] + x[base + 256 + tid];

    float mean = block_reduce_sum(v0 + v1, red, tid) * (1.0f / Dn);
    float d0 = v0 - mean, d1 = v1 - mean;
    float var = block_reduce_sum(d0 * d0 + d1 * d1, red, tid) * (1.0f / Dn);
    float inv = rsqrtf(var + 1e-5f);

    float o0 = d0 * inv * g[tid]       + be[tid];
    float o1 = d1 * inv * g[256 + tid] + be[256 + tid];
    x[base + tid]        = o0;
    x[base + 256 + tid]  = o1;
    xb[base + tid]       = (__bf16)o0;
    xb[base + 256 + tid] = (__bf16)o1;
}

// ---------------------------------------------------------------------------
// launcher
// ---------------------------------------------------------------------------
extern "C" void kernel_launch(void* const* d_in, const int* in_sizes, int n_in,
                              void* d_out, int out_size, void* d_ws, size_t ws_size,
                              hipStream_t stream)
{
    const float* x_in   = (const float*)d_in[0];
    const float* qkv_w  = (const float*)d_in[1];
    const float* qkv_b  = (const float*)d_in[2];
    const float* out_w  = (const float*)d_in[3];
    const float* out_b  = (const float*)d_in[4];
    const float* ln1_g  = (const float*)d_in[5];
    const float* ln1_b  = (const float*)d_in[6];
    const float* mlp_w1 = (const float*)d_in[7];
    const float* mlp_b1 = (const float*)d_in[8];
    const float* mlp_w2 = (const float*)d_in[9];
    const float* mlp_b2 = (const float*)d_in[10];
    const float* ln2_g  = (const float*)d_in[11];
    const float* ln2_b  = (const float*)d_in[12];

    // workspace layout (~94 MB)
    char* p = (char*)d_ws;
    float*  X    = (float*)p;  p += (size_t)Mn * Dn * 4;        // 16 MB fp32 residual
    __bf16* Xb   = (__bf16*)p; p += (size_t)Mn * Dn * 2;        //  8 MB bf16 x
    __bf16* QKVb = (__bf16*)p; p += (size_t)Mn * 3 * Dn * 2;    // 24 MB
    __bf16* AOb  = (__bf16*)p; p += (size_t)Mn * Dn * 2;        //  8 MB attn out
    __bf16* Hb   = (__bf16*)p; p += (size_t)Mn * DFFn * 2;      // 32 MB mlp hidden
    __bf16* Wq   = (__bf16*)p; p += (size_t)3 * Dn * Dn * 2;    // 1.5 MB  [1536][512]
    __bf16* Wo   = (__bf16*)p; p += (size_t)Dn * Dn * 2;        // 0.5 MB  [512][512]
    __bf16* W1   = (__bf16*)p; p += (size_t)DFFn * Dn * 2;      // 2 MB    [2048][512]
    __bf16* W2   = (__bf16*)p; p += (size_t)Dn * DFFn * 2;      // 2 MB    [512][2048]
    __bf16* Vt   = Hb;             // 8 MB, aliased: Hb dead during attention
    float* BUF3 = (float*)d_out;   // pre-LN temp lives in d_out

    const size_t xBytes = (size_t)Mn * Dn * sizeof(float);
    hipMemcpyAsync(X, x_in, xBytes, hipMemcpyDeviceToDevice, stream);
    k_cast_bf16<<<(Mn * Dn) / 256, 256, 0, stream>>>(x_in, Xb, Mn * Dn);

    for (int l = 0; l < Ln; l++) {
        // weight transpose+cast for this layer
        k_trans_cast<<<dim3(1536 / 32, 512 / 32), dim3(32, 8), 0, stream>>>(
            qkv_w + (size_t)l * Dn * 3 * Dn, Wq, Dn, 3 * Dn);
        k_trans_cast<<<dim3(512 / 32, 512 / 32), dim3(32, 8), 0, stream>>>(
            out_w + (size_t)l * Dn * Dn, Wo, Dn, Dn);
        k_trans_cast<<<dim3(2048 / 32, 512 / 32), dim3(32, 8), 0, stream>>>(
            mlp_w1 + (size_t)l * Dn * DFFn, W1, Dn, DFFn);
        k_trans_cast<<<dim3(512 / 32, 2048 / 32), dim3(32, 8), 0, stream>>>(
            mlp_w2 + (size_t)l * DFFn * Dn, W2, DFFn, Dn);

        // QKV projection -> bf16 [M,1536]
        k_gemm_mfma<0, 1, 4><<<dim3(12, 64), 256, 0, stream>>>(
            Xb, Wq, qkv_b + (size_t)l * 3 * Dn, QKVb, Mn, 3 * Dn, Dn);
        // V transpose: [s][d] -> [d][s] per (b,h)
        k_trans_v<<<dim3(Sn / 32, DKn / 32, Bn * Hn), dim3(32, 8), 0, stream>>>(QKVb, Vt);
        // MFMA flash attention -> bf16 [M,512]
        k_attn_mfma<<<dim3(Sn / 64, Hn, Bn), 256, 0, stream>>>(QKVb, Vt, AOb);
        // output projection -> fp32 BUF3
        k_gemm_mfma<0, 0, 2><<<dim3(8, 64), 256, 0, stream>>>(
            AOb, Wo, out_b + (size_t)l * Dn, BUF3, Mn, Dn, Dn);
        // x = LN(proj + x)
        k_residual_ln<<<Mn, 256, 0, stream>>>(BUF3, X, Xb,
            ln1_g + (size_t)l * Dn, ln1_b + (size_t)l * Dn);
        // MLP up + ReLU -> bf16 [M,2048]
        k_gemm_mfma<1, 1, 4><<<dim3(16, 64), 256, 0, stream>>>(
            Xb, W1, mlp_b1 + (size_t)l * DFFn, Hb, Mn, DFFn, Dn);
        // MLP down -> fp32 BUF3
        k_gemm_mfma<0, 0, 2><<<dim3(8, 64), 256, 0, stream>>>(
            Hb, W2, mlp_b2 + (size_t)l * Dn, BUF3, Mn, Dn, DFFn);
        // x = LN(x + mlp)
        k_residual_ln<<<Mn, 256, 0, stream>>>(BUF3, X, Xb,
            ln2_g + (size_t)l * Dn, ln2_b + (size_t)l * Dn);
    }

    hipMemcpyAsync(d_out, X, xBytes, hipMemcpyDeviceToDevice, stream);
}

// Round 6
// 1482.461 us; speedup vs baseline: 10.2086x; 1.0039x over previous
//
#include <hip/hip_runtime.h>
#include <math.h>

// Problem constants
#define Bn   8
#define Sn   1024
#define Dn   512
#define Hn   8
#define DKn  64
#define Ln   6
#define DFFn 2048
#define Mn   (Bn * Sn)   // 8192 rows

typedef __bf16 bf16x8 __attribute__((ext_vector_type(8)));
typedef __bf16 bf16x4 __attribute__((ext_vector_type(4)));
typedef float  f32x4  __attribute__((ext_vector_type(4)));

// async global->LDS, 16B per lane. LDS dest must be wave-uniform base + lane*16.
__device__ __forceinline__ void gl_lds16(const void* g, void* l) {
    __builtin_amdgcn_global_load_lds(
        (const __attribute__((address_space(1))) void*)g,
        (__attribute__((address_space(3))) void*)l, 16, 0, 0);
}

// ---------------------------------------------------------------------------
// fp32 -> bf16 cast
// ---------------------------------------------------------------------------
__global__ __launch_bounds__(256) void k_cast_bf16(const float* __restrict__ in,
                                                   __bf16* __restrict__ out, int n) {
    int i = blockIdx.x * 256 + threadIdx.x;
    if (i < n) out[i] = (__bf16)in[i];
}

// ---------------------------------------------------------------------------
// All 4 weight matrices of one layer: W[K][N] fp32 -> Wt[N][K] bf16.
// 32x32 tiles, 32x8 threads. Tile ranges: Wq 768 | Wo 256 | W1 1024 | W2 1024.
// ---------------------------------------------------------------------------
__global__ __launch_bounds__(256) void k_trans_all(
    const float* __restrict__ qkv_w, const float* __restrict__ out_w,
    const float* __restrict__ w1, const float* __restrict__ w2,
    __bf16* __restrict__ Wq, __bf16* __restrict__ Wo,
    __bf16* __restrict__ W1o, __bf16* __restrict__ W2o)
{
    const int t = blockIdx.x;
    const float* src; __bf16* dst; int K, N, n0, k0;
    if (t < 768)       { src = qkv_w; dst = Wq;  K = 512;  N = 1536; int u = t;        n0 = (u % 48) * 32; k0 = (u / 48) * 32; }
    else if (t < 1024) { src = out_w; dst = Wo;  K = 512;  N = 512;  int u = t - 768;  n0 = (u % 16) * 32; k0 = (u / 16) * 32; }
    else if (t < 2048) { src = w1;    dst = W1o; K = 512;  N = 2048; int u = t - 1024; n0 = (u % 64) * 32; k0 = (u / 64) * 32; }
    else               { src = w2;    dst = W2o; K = 2048; N = 512;  int u = t - 2048; n0 = (u % 16) * 32; k0 = (u / 16) * 32; }

    __shared__ float tt[32][33];
    const int tx = threadIdx.x, ty = threadIdx.y;
    #pragma unroll
    for (int r = 0; r < 4; r++)
        tt[ty + 8 * r][tx] = src[(size_t)(k0 + ty + 8 * r) * N + n0 + tx];
    __syncthreads();
    #pragma unroll
    for (int r = 0; r < 4; r++)
        dst[(size_t)(n0 + ty + 8 * r) * K + k0 + tx] = (__bf16)tt[tx][ty + 8 * r];
}

// ---------------------------------------------------------------------------
// MFMA GEMM: C[M,N] = act(A[M,K]bf16 @ Bt[N,K]bf16^T + bias[N]fp32)
// Block: 256 thr = 4 waves (2x2). Tile: 128 x (JT*32). BK=64.
// A/B fragment: elem[j] = X[lane&15][ (lane>>4)*8 + j ]  (m97-verified)
// C/D: col = lane&15, row = (lane>>4)*4 + reg            (m89/m91-verified)
// VW=1 (QKV only): cols >=1024 are V -> also scatter into Vt[b*8+h][d][s].
// ---------------------------------------------------------------------------
template <int RELU, int OUTBF, int JT, int VW>
__global__ __launch_bounds__(256) void k_gemm_mfma(
    const __bf16* __restrict__ A, const __bf16* __restrict__ Bt,
    const float* __restrict__ bias, void* __restrict__ Cout,
    __bf16* __restrict__ Vt, int M, int N, int K)
{
    constexpr int BN = JT * 32;   // 128 or 64
    __shared__ __bf16 As[128][64];
    __shared__ __bf16 Bs[BN][64];
    const int tid  = threadIdx.x;
    const int lane = tid & 63;
    const int wave = tid >> 6;
    const int wy   = wave >> 1, wx = wave & 1;
    const int m16  = lane & 15, quad = lane >> 4;
    const int bm   = blockIdx.y * 128, bn = blockIdx.x * BN;

    f32x4 acc[4][JT];
    #pragma unroll
    for (int i = 0; i < 4; i++)
        #pragma unroll
        for (int j = 0; j < JT; j++)
            acc[i][j] = (f32x4){0.f, 0.f, 0.f, 0.f};

    const __bf16* Ap = A  + (size_t)bm * K;
    const __bf16* Bp = Bt + (size_t)bn * K;

    for (int k0 = 0; k0 < K; k0 += 64) {
        __syncthreads();
        #pragma unroll
        for (int c = 0; c < 4; c++) {           // A: 128x64 bf16 = 1024 x 16B
            int lin = tid + c * 256;
            int row = lin >> 3, kc = (lin & 7) << 3;
            gl_lds16(Ap + (size_t)row * K + k0 + kc, (void*)(&As[0][0] + lin * 8));
        }
        #pragma unroll
        for (int c = 0; c < JT; c++) {          // B: BNx64 bf16
            int lin = tid + c * 256;
            int row = lin >> 3, kc = (lin & 7) << 3;
            gl_lds16(Bp + (size_t)row * K + k0 + kc, (void*)(&Bs[0][0] + lin * 8));
        }
        __syncthreads();

        bf16x8 af[4][2], bfr[JT][2];
        #pragma unroll
        for (int i = 0; i < 4; i++) {
            af[i][0] = *(const bf16x8*)&As[wy * 64 + i * 16 + m16][quad * 8];
            af[i][1] = *(const bf16x8*)&As[wy * 64 + i * 16 + m16][32 + quad * 8];
        }
        #pragma unroll
        for (int j = 0; j < JT; j++) {
            bfr[j][0] = *(const bf16x8*)&Bs[wx * JT * 16 + j * 16 + m16][quad * 8];
            bfr[j][1] = *(const bf16x8*)&Bs[wx * JT * 16 + j * 16 + m16][32 + quad * 8];
        }
        #pragma unroll
        for (int hc = 0; hc < 2; hc++)
            #pragma unroll
            for (int i = 0; i < 4; i++)
                #pragma unroll
                for (int j = 0; j < JT; j++)
                    acc[i][j] = __builtin_amdgcn_mfma_f32_16x16x32_bf16(
                        af[i][hc], bfr[j][hc], acc[i][j], 0, 0, 0);
    }

    float*  Cf = (float*)Cout;
    __bf16* Cb = (__bf16*)Cout;
    #pragma unroll
    for (int i = 0; i < 4; i++) {
        const int row0 = bm + wy * 64 + i * 16 + quad * 4;
        #pragma unroll
        for (int j = 0; j < JT; j++) {
            const int col = bn + wx * JT * 16 + j * 16 + m16;
            const float bv = bias[col];
            float vv[4];
            #pragma unroll
            for (int r = 0; r < 4; r++) {
                float v = acc[i][j][r] + bv;
                if (RELU) v = fmaxf(v, 0.f);
                vv[r] = v;
                if (OUTBF) Cb[(size_t)(row0 + r) * N + col] = (__bf16)v;
                else       Cf[(size_t)(row0 + r) * N + col] = v;
            }
            if (VW && col >= 1024) {            // V slice -> Vt[b*8+h][d][s]
                const int cc = col - 1024;
                const int bb = row0 >> 10, ss = row0 & 1023;
                bf16x4 pv;
                #pragma unroll
                for (int r = 0; r < 4; r++) pv[r] = (__bf16)vv[r];
                *(bf16x4*)&Vt[((size_t)(bb * Hn + (cc >> 6)) * DKn + (cc & 63)) * Sn + ss] = pv;
            }
        }
    }
}

// ---------------------------------------------------------------------------
// Barrier-free MFMA flash attention (causal).
// qkv: [M][1536] bf16; Vt: [b*8+h][64][1024] bf16.
// Block = (pair pr, h, b): handles q-tiles qtA=pr and qtB=15-pr (uniform 17
// MFMA-tiles). 4 waves, wave w owns q-rows w*16..+15 of each tile.
// K/V fragments load DIRECTLY global->VGPR (16B/lane); no K/V LDS, no
// __syncthreads in the k-loop. Only LDS: per-wave P scratch (C/D -> A layout).
// Online softmax in registers via width-16 shfl_xor.
// ---------------------------------------------------------------------------
__device__ __forceinline__ void softmax_update(
    f32x4 sv[4], float m[4], float l[4], f32x4 acc[4],
    bool diag, int wave16, int quad, int m16,
    __bf16 (*Pw)[72], bf16x8& pf0, bf16x8& pf1)
{
    #pragma unroll
    for (int j = 0; j < 4; j++)
        #pragma unroll
        for (int r = 0; r < 4; r++) {
            float v = sv[j][r] * 0.125f;    // 1/sqrt(64)
            if (diag && (j * 16 + m16) > (wave16 + quad * 4 + r)) v = -1e30f;
            sv[j][r] = v;
        }

    float pm[4];
    #pragma unroll
    for (int r = 0; r < 4; r++)
        pm[r] = fmaxf(fmaxf(sv[0][r], sv[1][r]), fmaxf(sv[2][r], sv[3][r]));
    #pragma unroll
    for (int off = 1; off < 16; off <<= 1)
        #pragma unroll
        for (int r = 0; r < 4; r++)
            pm[r] = fmaxf(pm[r], __shfl_xor(pm[r], off, 16));

    float al[4];
    #pragma unroll
    for (int r = 0; r < 4; r++) {
        float mn = fmaxf(m[r], pm[r]);
        al[r] = __expf(m[r] - mn);
        m[r] = mn;
    }

    float rs[4] = {0.f, 0.f, 0.f, 0.f};
    #pragma unroll
    for (int j = 0; j < 4; j++)
        #pragma unroll
        for (int r = 0; r < 4; r++) {
            float p = __expf(sv[j][r] - m[r]);
            rs[r] += p;
            Pw[quad * 4 + r][j * 16 + m16] = (__bf16)p;
        }
    #pragma unroll
    for (int off = 1; off < 16; off <<= 1)
        #pragma unroll
        for (int r = 0; r < 4; r++)
            rs[r] += __shfl_xor(rs[r], off, 16);
    #pragma unroll
    for (int r = 0; r < 4; r++) l[r] = l[r] * al[r] + rs[r];

    #pragma unroll
    for (int j = 0; j < 4; j++)
        #pragma unroll
        for (int r = 0; r < 4; r++) acc[j][r] *= al[r];

    pf0 = *(const bf16x8*)&Pw[m16][quad * 8];
    pf1 = *(const bf16x8*)&Pw[m16][32 + quad * 8];
}

__global__ __launch_bounds__(256) void k_attn_mfma(
    const __bf16* __restrict__ qkv, const __bf16* __restrict__ Vt,
    __bf16* __restrict__ o)
{
    const int pr  = blockIdx.x;          // 0..7
    const int h   = blockIdx.y;
    const int b   = blockIdx.z;
    const int tid  = threadIdx.x;
    const int lane = tid & 63, wave = tid >> 6;
    const int m16  = lane & 15, quad = lane >> 4;
    const int qtA  = pr, qtB = 15 - pr;
    const int wave16 = wave * 16;

    __shared__ __bf16 Ps[4][16][72];     // per-wave P scratch, rows 144B (16B-aligned)

    const __bf16* base = qkv + (size_t)b * Sn * 1536 + h * DKn;   // Q +0, K +512
    const __bf16* vtb  = Vt + (size_t)(b * Hn + h) * DKn * Sn;

    bf16x8 qA0, qA1, qB0, qB1;
    {
        const __bf16* qa = base + (size_t)(qtA * 64 + wave16 + m16) * 1536 + quad * 8;
        qA0 = *(const bf16x8*)qa; qA1 = *(const bf16x8*)(qa + 32);
        const __bf16* qb = base + (size_t)(qtB * 64 + wave16 + m16) * 1536 + quad * 8;
        qB0 = *(const bf16x8*)qb; qB1 = *(const bf16x8*)(qb + 32);
    }

    float mA[4], lA[4], mB[4], lB[4];
    f32x4 accA[4], accB[4];
    #pragma unroll
    for (int r = 0; r < 4; r++) {
        mA[r] = -1e30f; lA[r] = 0.f; mB[r] = -1e30f; lB[r] = 0.f;
        accA[r] = (f32x4){0.f, 0.f, 0.f, 0.f};
        accB[r] = (f32x4){0.f, 0.f, 0.f, 0.f};
    }

    for (int kt = 0; kt <= qtB; kt++) {
        const int k0 = kt * 64;
        const bool actA = (kt <= qtA);

        // ---- S = Q K^T (K fragments direct from global; shared by A & B) ----
        f32x4 svA[4], svB[4];
        #pragma unroll
        for (int j = 0; j < 4; j++) {
            const __bf16* kp = base + (size_t)(k0 + j * 16 + m16) * 1536 + 512 + quad * 8;
            bf16x8 kf0 = *(const bf16x8*)kp;
            bf16x8 kf1 = *(const bf16x8*)(kp + 32);
            f32x4 s = (f32x4){0.f, 0.f, 0.f, 0.f};
            s = __builtin_amdgcn_mfma_f32_16x16x32_bf16(qB0, kf0, s, 0, 0, 0);
            s = __builtin_amdgcn_mfma_f32_16x16x32_bf16(qB1, kf1, s, 0, 0, 0);
            svB[j] = s;
            if (actA) {
                f32x4 s2 = (f32x4){0.f, 0.f, 0.f, 0.f};
                s2 = __builtin_amdgcn_mfma_f32_16x16x32_bf16(qA0, kf0, s2, 0, 0, 0);
                s2 = __builtin_amdgcn_mfma_f32_16x16x32_bf16(qA1, kf1, s2, 0, 0, 0);
                svA[j] = s2;
            }
        }

        // ---- online softmax (per-wave LDS round-trip, in-order DS) ----
        bf16x8 pB0, pB1, pA0, pA1;
        softmax_update(svB, mB, lB, accB, kt == qtB, wave16, quad, m16, Ps[wave], pB0, pB1);
        if (actA)
            softmax_update(svA, mA, lA, accA, kt == qtA, wave16, quad, m16, Ps[wave], pA0, pA1);

        // ---- O += P V (V fragments direct from global; shared by A & B) ----
        #pragma unroll
        for (int jd = 0; jd < 4; jd++) {
            const __bf16* vp = vtb + (size_t)(jd * 16 + m16) * Sn + k0 + quad * 8;
            bf16x8 vf0 = *(const bf16x8*)vp;
            bf16x8 vf1 = *(const bf16x8*)(vp + 32);
            accB[jd] = __builtin_amdgcn_mfma_f32_16x16x32_bf16(pB0, vf0, accB[jd], 0, 0, 0);
            accB[jd] = __builtin_amdgcn_mfma_f32_16x16x32_bf16(pB1, vf1, accB[jd], 0, 0, 0);
            if (actA) {
                accA[jd] = __builtin_amdgcn_mfma_f32_16x16x32_bf16(pA0, vf0, accA[jd], 0, 0, 0);
                accA[jd] = __builtin_amdgcn_mfma_f32_16x16x32_bf16(pA1, vf1, accA[jd], 0, 0, 0);
            }
        }
    }

    // epilogue: O / l for both tiles
    #pragma unroll
    for (int r = 0; r < 4; r++) { lA[r] = 1.0f / lA[r]; lB[r] = 1.0f / lB[r]; }
    #pragma unroll
    for (int jd = 0; jd < 4; jd++)
        #pragma unroll
        for (int r = 0; r < 4; r++) {
            const int rowA = b * Sn + qtA * 64 + wave16 + quad * 4 + r;
            const int rowB = b * Sn + qtB * 64 + wave16 + quad * 4 + r;
            o[(size_t)rowA * Dn + h * DKn + jd * 16 + m16] = (__bf16)(accA[jd][r] * lA[r]);
            o[(size_t)rowB * Dn + h * DKn + jd * 16 + m16] = (__bf16)(accB[jd][r] * lB[r]);
        }
}

// ---------------------------------------------------------------------------
// x = LayerNorm(t + x); writes fp32 x and bf16 copy xb.
// ---------------------------------------------------------------------------
__device__ inline float block_reduce_sum(float v, float* red, int tid) {
    red[tid] = v;
    __syncthreads();
    for (int s = 128; s > 0; s >>= 1) {
        if (tid < s) red[tid] += red[tid + s];
        __syncthreads();
    }
    float r = red[0];
    __syncthreads();
    return r;
}

__global__ __launch_bounds__(256) void k_residual_ln(
    const float* __restrict__ t, float* __restrict__ x, __bf16* __restrict__ xb,
    const float* __restrict__ g, const float* __restrict__ be)
{
    __shared__ float red[256];
    const int row = blockIdx.x, tid = threadIdx.x;
    const size_t base = (size_t)row * Dn;

    float v0 = t[base + tid] + x[base + tid];
    float v1 = t[base + 256 + tid] + x[base + 256 + tid];

    float mean = block_reduce_sum(v0 + v1, red, tid) * (1.0f / Dn);
    float d0 = v0 - mean, d1 = v1 - mean;
    float var = block_reduce_sum(d0 * d0 + d1 * d1, red, tid) * (1.0f / Dn);
    float inv = rsqrtf(var + 1e-5f);

    float o0 = d0 * inv * g[tid]       + be[tid];
    float o1 = d1 * inv * g[256 + tid] + be[256 + tid];
    x[base + tid]        = o0;
    x[base + 256 + tid]  = o1;
    xb[base + tid]       = (__bf16)o0;
    xb[base + 256 + tid] = (__bf16)o1;
}

// ---------------------------------------------------------------------------
// launcher
// ---------------------------------------------------------------------------
extern "C" void kernel_launch(void* const* d_in, const int* in_sizes, int n_in,
                              void* d_out, int out_size, void* d_ws, size_t ws_size,
                              hipStream_t stream)
{
    const float* x_in   = (const float*)d_in[0];
    const float* qkv_w  = (const float*)d_in[1];
    const float* qkv_b  = (const float*)d_in[2];
    const float* out_w  = (const float*)d_in[3];
    const float* out_b  = (const float*)d_in[4];
    const float* ln1_g  = (const float*)d_in[5];
    const float* ln1_b  = (const float*)d_in[6];
    const float* mlp_w1 = (const float*)d_in[7];
    const float* mlp_b1 = (const float*)d_in[8];
    const float* mlp_w2 = (const float*)d_in[9];
    const float* mlp_b2 = (const float*)d_in[10];
    const float* ln2_g  = (const float*)d_in[11];
    const float* ln2_b  = (const float*)d_in[12];

    // workspace layout (~94 MB)
    char* p = (char*)d_ws;
    float*  X    = (float*)p;  p += (size_t)Mn * Dn * 4;        // 16 MB fp32 residual
    __bf16* Xb   = (__bf16*)p; p += (size_t)Mn * Dn * 2;        //  8 MB bf16 x
    __bf16* QKVb = (__bf16*)p; p += (size_t)Mn * 3 * Dn * 2;    // 24 MB
    __bf16* AOb  = (__bf16*)p; p += (size_t)Mn * Dn * 2;        //  8 MB attn out
    __bf16* Hb   = (__bf16*)p; p += (size_t)Mn * DFFn * 2;      // 32 MB mlp hidden
    __bf16* Wq   = (__bf16*)p; p += (size_t)3 * Dn * Dn * 2;    // 1.5 MB  [1536][512]
    __bf16* Wo   = (__bf16*)p; p += (size_t)Dn * Dn * 2;        // 0.5 MB  [512][512]
    __bf16* W1   = (__bf16*)p; p += (size_t)DFFn * Dn * 2;      // 2 MB    [2048][512]
    __bf16* W2   = (__bf16*)p; p += (size_t)Dn * DFFn * 2;      // 2 MB    [512][2048]
    __bf16* Vt   = Hb;             // 8 MB, aliased: Hb dead during attention
    float* BUF3 = (float*)d_out;   // pre-LN temp lives in d_out

    const size_t xBytes = (size_t)Mn * Dn * sizeof(float);
    hipMemcpyAsync(X, x_in, xBytes, hipMemcpyDeviceToDevice, stream);
    k_cast_bf16<<<(Mn * Dn) / 256, 256, 0, stream>>>(x_in, Xb, Mn * Dn);

    for (int l = 0; l < Ln; l++) {
        // all 4 weight transposes in one launch
        k_trans_all<<<3072, dim3(32, 8), 0, stream>>>(
            qkv_w + (size_t)l * Dn * 3 * Dn, out_w + (size_t)l * Dn * Dn,
            mlp_w1 + (size_t)l * Dn * DFFn, mlp_w2 + (size_t)l * DFFn * Dn,
            Wq, Wo, W1, W2);

        // QKV projection -> bf16 [M,1536] + fused Vt scatter
        k_gemm_mfma<0, 1, 4, 1><<<dim3(12, 64), 256, 0, stream>>>(
            Xb, Wq, qkv_b + (size_t)l * 3 * Dn, QKVb, Vt, Mn, 3 * Dn, Dn);
        // barrier-free MFMA flash attention -> bf16 [M,512]
        k_attn_mfma<<<dim3(8, Hn, Bn), 256, 0, stream>>>(QKVb, Vt, AOb);
        // output projection -> fp32 BUF3
        k_gemm_mfma<0, 0, 2, 0><<<dim3(8, 64), 256, 0, stream>>>(
            AOb, Wo, out_b + (size_t)l * Dn, BUF3, nullptr, Mn, Dn, Dn);
        // x = LN(proj + x)
        k_residual_ln<<<Mn, 256, 0, stream>>>(BUF3, X, Xb,
            ln1_g + (size_t)l * Dn, ln1_b + (size_t)l * Dn);
        // MLP up + ReLU -> bf16 [M,2048]  (overwrites Vt alias; attn done)
        k_gemm_mfma<1, 1, 4, 0><<<dim3(16, 64), 256, 0, stream>>>(
            Xb, W1, mlp_b1 + (size_t)l * DFFn, Hb, nullptr, Mn, DFFn, Dn);
        // MLP down -> fp32 BUF3
        k_gemm_mfma<0, 0, 2, 0><<<dim3(8, 64), 256, 0, stream>>>(
            Hb, W2, mlp_b2 + (size_t)l * Dn, BUF3, nullptr, Mn, Dn, DFFn);
        // x = LN(x + mlp)
        k_residual_ln<<<Mn, 256, 0, stream>>>(BUF3, X, Xb,
            ln2_g + (size_t)l * Dn, ln2_b + (size_t)l * Dn);
    }

    hipMemcpyAsync(d_out, X, xBytes, hipMemcpyDeviceToDevice, stream);
}